// Round 20
// baseline (3289.102 us; speedup 1.0000x reference)
//
#include <hip/hip_runtime.h>
#include <stdint.h>

// Online Neural CDE — R20: R19 (2552us) reshaped to 1024-thread blocks with
// __launch_bounds__(1024, 4): 4 waves/SIMD pinned -> VGPR cap 128 (not R14's
// 64-cap spill trap), 16 waves/CU for 2x latency hiding on the L2 weight
// stream. Per-thread work halves (L4 1 row/thread, mids quarter-rows).
// Everything else identical to R19: pair-split (batch b = blocks b, b+128;
// L4 split by h-half; redundant L1/m0/m1), int16 weights + fp32 activations,
// tagged double-banked k-exchange, lgkm-only barriers, fast tanh/softplus,
// precomputed dx table. Revert criteria: VGPR=64 / WRITE_SIZE>>1MB / slower.

#define NB   256
#define NTHR 1024

// d_ws byte layout (total 1,649,664 B)
#define SC_OFF   0u        // 2816 f32 scales
#define WV_OFF   11264u    // 64 KB
#define WM1_OFF  76800u    // 128 KB
#define WL4_OFF  207872u   // 1 MB (2 sets x 512 KB)
#define WM0_OFF  1256448u  // 128 KB
#define EX_OFF   1387520u  // 128 batches x 2 sets x 2 banks x 64 u64 = 256 KB

typedef unsigned long long u64t;

static __device__ __forceinline__ u64t ld_coh8(const u64t* p) {
  return __hip_atomic_load(p, __ATOMIC_RELAXED, __HIP_MEMORY_SCOPE_AGENT);
}
static __device__ __forceinline__ void st_coh8(u64t* p, u64t v) {
  __hip_atomic_store(p, v, __ATOMIC_RELAXED, __HIP_MEMORY_SCOPE_AGENT);
}
static __device__ __forceinline__ u64t pack_tf(float f, uint32_t tag) {
  union { float f; uint32_t u; } c; c.f = f;
  return ((u64t)tag << 32) | c.u;
}
static __device__ __forceinline__ float low_f(u64t v) {
  union { uint32_t u; float f; } c; c.u = (uint32_t)v;
  return c.f;
}

static __device__ __forceinline__ float qmac2(uint32_t q, float h0, float h1, float acc) {
  acc = fmaf((float)(short)(q & 0xffffu), h0, acc);
  return fmaf((float)(short)(q >> 16), h1, acc);
}

// fast softplus: max(x,0) + log(1+exp(-|x|)) via hardware exp2/log2
static __device__ __forceinline__ float sp_fast(float x) {
  return fmaxf(x, 0.f) + __logf(1.f + __expf(-fabsf(x)));
}
// precise softplus (init only)
static __device__ __forceinline__ float sp(float x) {
  return fmaxf(x, 0.f) + log1pf(expf(-fabsf(x)));
}
// fast tanh via __expf + v_rcp; saturates correctly for large |x|
static __device__ __forceinline__ float tanh_fast(float x) {
  float ax = fabsf(x);
  float e = __expf(ax + ax);
  float t = 1.f - 2.f * __builtin_amdgcn_rcpf(e + 1.f);
  return __builtin_copysignf(t, x);
}

// LDS-only barrier: orders all LDS traffic, leaves global loads in flight.
static __device__ __forceinline__ void lbar() {
  asm volatile("s_waitcnt lgkmcnt(0)\n\ts_barrier" ::: "memory");
}

// np.searchsorted(kn, t, 'right') - 1, clipped to [0, 62]; 64 knots.
static __device__ __forceinline__ int seg_idx(const float* kn, float t) {
  int lo = 0, hi = 64;
  while (lo < hi) { int mid = (lo + hi) >> 1; if (kn[mid] <= t) lo = mid + 1; else hi = mid; }
  int jj = lo - 1;
  return jj < 0 ? 0 : (jj > 62 ? 62 : jj);
}

// ---- prep: per-row int16 quantization into 1024-lane chunk-tiled layouts ----
__global__ void prep_kernel(const float* __restrict__ v_win,
                            const float* __restrict__ v_wmid,
                            const float* __restrict__ v_wout,
                            unsigned char* __restrict__ wsb) {
  float* scales = (float*)(wsb + SC_OFF);
  short* wv  = (short*)(wsb + WV_OFF);
  short* wm1 = (short*)(wsb + WM1_OFF);
  short* wl4 = (short*)(wsb + WL4_OFF);
  short* wm0 = (short*)(wsb + WM0_OFF);
  const int r = blockIdx.x, lane = threadIdx.x;
  const float* src;
  int n;
  if (r < 256)       { src = v_win  + (size_t)r * 128;                 n = 128; }
  else if (r < 512)  { src = v_wmid + 65536 + (size_t)(r - 256) * 256; n = 256; }
  else if (r < 2560) { src = v_wout + (size_t)(r - 512) * 256;         n = 256; }
  else               { src = v_wmid + (size_t)(r - 2560) * 256;        n = 256; }
  float m = 0.f;
  for (int i = lane; i < n; i += 64) m = fmaxf(m, fabsf(src[i]));
#pragma unroll
  for (int off = 32; off; off >>= 1) m = fmaxf(m, __shfl_xor(m, off));
  const float inv = (m > 0.f) ? 32767.f / m : 0.f;
  if (lane == 0) scales[r] = (m > 0.f) ? m / 32767.f : 1.f;
  for (int i = lane; i < n; i += 64) {
    short qv = (short)rintf(src[i] * inv);
    if (r < 256) {
      // read: thread tt=4r+q (q=i>>5), chunk c=(i&31)>>3, elem e=i&7
      int qd = i >> 5, c = (i & 31) >> 3, e = i & 7;
      wv[(c * 1024 + 4 * r + qd) * 8 + e] = qv;
    } else if (r < 512) {
      int row = r - 256;
      int qd = i >> 6, c = (i & 63) >> 3, e = i & 7;
      wm1[(c * 1024 + 4 * row + qd) * 8 + e] = qv;
    } else if (r < 2560) {
      int row = r - 512;               // 0..2047 = h*16 + d
      int s = row >> 10, row_s = row & 1023;   // thread tt == row_s
      int c = i >> 3, e = i & 7;
      wl4[s * 262144 + (c * 1024 + row_s) * 8 + e] = qv;
    } else {
      int row = r - 2560;
      wm0[(size_t)row * 256 + i] = qv;
    }
  }
}

__global__ void __launch_bounds__(NTHR, 4)
ncde_kernel(const float* __restrict__ ts, const float* __restrict__ tsi,
            const float* __restrict__ obs, const float* __restrict__ tmax,
            const float* __restrict__ i_win, const float* __restrict__ i_bin,
            const float* __restrict__ i_wmid, const float* __restrict__ i_bmid,
            const float* __restrict__ i_wout, const float* __restrict__ i_bout,
            const float* __restrict__ v_wmid, const float* __restrict__ v_bin,
            const float* __restrict__ v_bmid, const float* __restrict__ v_bout,
            unsigned char* __restrict__ wsb, float* __restrict__ out) {
  __shared__ __align__(16) uint32_t s_m0[256][132];   // int16-pair m0, swizzled
  __shared__ __align__(16) float s_yin[128];
  __shared__ __align__(16) float s_h1[256];
  __shared__ __align__(16) float s_h2[256];
  __shared__ __align__(16) float s_h3[256];
  __shared__ __align__(16) float s_ts[64];
  __shared__ __align__(16) float s_kn[64];
  __shared__ __align__(16) float s_dxt[127][16];      // dx table per (ti, d)
  __shared__ float s_y[128];    // full ODE state (bit-identical in both blocks)
  __shared__ float s_k[128];    // latest k (own half local, partner via poll)
  __shared__ float s_ka[128];   // RK4 accumulator
  __shared__ float s_x0[16];
  __shared__ unsigned char s_sj[128];

  const int t = threadIdx.x;
  const int bid = blockIdx.x;
  const int b = bid & 127;      // batch
  const int s = bid >> 7;       // half: s=0 rows h 0..63, s=1 rows 64..127
  const int o = t >> 2, q = t & 3;     // L1/m0/m1 map (o<256)
  const int dL = t & 15, hl = t >> 4;  // L4 map: set-row = t = hl*16+dL

  const float* scales = (const float*)(wsb + SC_OFF);
  const uint4* wvp  = ((const uint4*)(wsb + WV_OFF)) + t;            // c<4
  const uint4* wm1p = ((const uint4*)(wsb + WM1_OFF)) + t;           // c<8
  const uint4* wl4p = ((const uint4*)(wsb + WL4_OFF)) + s * 32768 + t; // c<32
  u64t* exb    = ((u64t*)(wsb + EX_OFF)) + (size_t)b * 256;
  u64t* ex_own = exb + s * 128;          // [2 banks][64]
  u64t* expart = exb + (1 - s) * 128;

  if (t < 64) { s_ts[t] = ts[b * 64 + t]; s_kn[t] = tsi[b * 64 + t]; }
  const float tm = tmax[b];
  const float bl1 = v_bin[o];
  const float bm0 = v_bmid[o];
  const float bm1 = v_bmid[256 + o];
  const float sc_wv = scales[o];
  const float sc_m1 = scales[256 + o];
  const float sc_m0 = scales[2560 + o];
  const float scl4f = scales[512 + s * 1024 + t];   // L4 row = s*1024 + t
  const float vbf   = v_bout[s * 1024 + t];
  __syncthreads();

  // m0 -> LDS (coalesced u32 copy, quartet-breaking swizzle on cols)
  {
    const uint32_t* wm0u = (const uint32_t*)(wsb + WM0_OFF);
    for (int idx = t; idx < 32768; idx += NTHR) {
      int row = idx >> 7, k = idx & 127;
      s_m0[row][k ^ (((row >> 3) & 3) << 2)] = wm0u[idx];
    }
  }
  if (t < 127) {
    int li = t >> 1;
    float te = (t & 1) ? fmaf(0.5f, s_ts[li + 1] - s_ts[li], s_ts[li]) : s_ts[li];
    s_sj[t] = (unsigned char)seg_idx(s_kn, te);
  }
  __syncthreads();

  // precompute dx table: s_dxt[ti][d]
  for (int idx = t; idx < 127 * 16; idx += NTHR) {
    int ti = idx >> 4, d = idx & 15;
    int sj = s_sj[ti];
    const float* ob = obs + ((size_t)b * 64 + sj) * 16 + d;
    s_dxt[ti][d] = (ob[16] - ob[0]) / (s_kn[sj + 1] - s_kn[sj]);
  }

  // ---------------- init MLP: y0 = MLP_i(x0) (redundant in both blocks) ----
  if (t < 16) {
    float t0 = s_ts[0];
    int sj = seg_idx(s_kn, t0);
    float k0 = s_kn[sj], k1 = s_kn[sj + 1];
    float fr = (t0 - k0) / (k1 - k0);
    const float* ob = obs + ((size_t)b * 64 + sj) * 16 + t;
    s_x0[t] = fmaf(fr, ob[16] - ob[0], ob[0]);
  }
  __syncthreads();
  if (t < 256) {                       // L1i: row t, 16 ins
    float acc = i_bin[t];
    const float* wr = i_win + (size_t)t * 16;
#pragma unroll
    for (int i = 0; i < 16; ++i) acc = fmaf(wr[i], s_x0[i], acc);
    s_h1[t] = sp(acc);
  }
  __syncthreads();
  if (t < 512) {                       // m0i: oi, half over 128 ins
    int oi = t >> 1, hf = t & 1;
    float acc = 0.f;
    const float4* wq = (const float4*)(i_wmid + (size_t)oi * 256 + hf * 128);
    const float4* hp = (const float4*)(s_h1 + hf * 128);
#pragma unroll
    for (int i = 0; i < 32; ++i) {
      float4 w = wq[i]; float4 hh = hp[i];
      acc = fmaf(w.x, hh.x, acc); acc = fmaf(w.y, hh.y, acc);
      acc = fmaf(w.z, hh.z, acc); acc = fmaf(w.w, hh.w, acc);
    }
    acc += __shfl_xor(acc, 1);
    if (!hf) s_h2[oi] = sp(acc + i_bmid[oi]);
  }
  __syncthreads();
  if (t < 512) {                       // m1i
    int oi = t >> 1, hf = t & 1;
    float acc = 0.f;
    const float4* wq = (const float4*)(i_wmid + 65536 + (size_t)oi * 256 + hf * 128);
    const float4* hp = (const float4*)(s_h2 + hf * 128);
#pragma unroll
    for (int i = 0; i < 32; ++i) {
      float4 w = wq[i]; float4 hh = hp[i];
      acc = fmaf(w.x, hh.x, acc); acc = fmaf(w.y, hh.y, acc);
      acc = fmaf(w.z, hh.z, acc); acc = fmaf(w.w, hh.w, acc);
    }
    acc += __shfl_xor(acc, 1);
    if (!hf) s_h3[oi] = sp(acc + i_bmid[256 + oi]);
  }
  __syncthreads();
  if (t < 512) {                       // L4i: 128 rows; h=t>>2, quarter t&3
    float acc = 0.f;
    const float4* wq = (const float4*)(i_wout + (size_t)(t >> 2) * 256 + (t & 3) * 64);
    const float4* hp = (const float4*)(s_h3 + (t & 3) * 64);
#pragma unroll
    for (int i = 0; i < 16; ++i) {
      float4 w = wq[i]; float4 hh = hp[i];
      acc = fmaf(w.x, hh.x, acc); acc = fmaf(w.y, hh.y, acc);
      acc = fmaf(w.z, hh.z, acc); acc = fmaf(w.w, hh.w, acc);
    }
    acc += __shfl_xor(acc, 1);
    acc += __shfl_xor(acc, 2);
    if ((t & 3) == 0) {
      int h = t >> 2;
      float y0 = acc + i_bout[h];
      s_y[h] = y0;
      if (s == 0)
        out[(size_t)b * 8192 + h] = (s_ts[0] <= tm) ? y0 : -99.f;
    }
  }
  __syncthreads();

  // ---------------- RK4 over 63 intervals, paired half-split --------------
#pragma unroll 1
  for (int l = 0; l < 63; ++l) {
    const float dt = s_ts[l + 1] - s_ts[l];
    const float dtp = (l > 0) ? (s_ts[l] - s_ts[l - 1]) : 0.f;
#pragma unroll 1
    for (int e = 0; e < 4; ++e) {
      const int ti = 2 * l + ((e == 0) ? 0 : ((e == 3) ? 2 : 1));
      // ---- phase 0: merge k (own LDS / partner poll), update state, y_in --
      auto upd = [&](int h, float kv) {
        if (e == 0) {                  // l > 0: finish prev eval, start new
          float ka = s_ka[h] + kv;
          float yn = fmaf(dtp * (1.f / 6.f), ka, s_y[h]);
          s_y[h] = yn;
          s_yin[h] = yn;
          if (s == 0)
            out[(size_t)b * 8192 + (size_t)l * 128 + h] =
                (s_ts[l] <= tm) ? yn : -99.f;
        } else {
          float ka = (e == 1) ? kv : fmaf(2.f, kv, s_ka[h]);
          s_ka[h] = ka;
          float ce = (e == 3) ? 1.f : 0.5f;
          s_yin[h] = fmaf(ce * dt, kv, s_y[h]);
        }
      };
      if (l == 0 && e == 0) {
        if (t < 128) s_yin[t] = s_y[t];
      } else {
        const uint32_t tg = (uint32_t)(l * 4 + e);   // partner's last publish
        if (t < 64) {
          u64t* pw = expart + ((tg & 1) << 6) + t;
          u64t v = ld_coh8(pw);
          uint32_t n = 0;
          while ((uint32_t)(v >> 32) != tg) {
            if (n > 8) __builtin_amdgcn_s_sleep(8);
            else       __builtin_amdgcn_s_sleep(1);
            if (++n > (1u << 14)) break;   // bounded failsafe
            v = ld_coh8(pw);
          }
          upd((1 - s) * 64 + t, low_f(v));
        } else if (t < 128) {
          int ho = s * 64 + (t - 64);
          upd(ho, s_k[ho]);
        }
      }
      lbar();
      // ---- L1 (streamed int16): row o, quarter q over 32 y-ins ----
      {
        float acc = 0.f;
#pragma unroll
        for (int c = 0; c < 4; ++c) {
          uint4 w = wvp[c * 1024];
          float4 ya = *(const float4*)(s_yin + q * 32 + 8 * c);
          float4 yb = *(const float4*)(s_yin + q * 32 + 8 * c + 4);
          acc = qmac2(w.x, ya.x, ya.y, acc);
          acc = qmac2(w.y, ya.z, ya.w, acc);
          acc = qmac2(w.z, yb.x, yb.y, acc);
          acc = qmac2(w.w, yb.z, yb.w, acc);
        }
        acc += __shfl_xor(acc, 1);
        acc += __shfl_xor(acc, 2);
        if (q == 0) s_h1[o] = sp_fast(acc * sc_wv + bl1);
      }
      lbar();
      // ---- m0 (LDS int16): row o, quarter q over 64 ins ----
      {
        float acc = 0.f;
        const int swz = ((o >> 3) & 3) << 2;
        const uint32_t* wr = &s_m0[o][0];
#pragma unroll
        for (int k = 0; k < 8; ++k) {
          uint4 w = *(const uint4*)(wr + ((q * 32 + 4 * k) ^ swz));
          float4 ha = *(const float4*)(s_h1 + q * 64 + 8 * k);
          float4 hb = *(const float4*)(s_h1 + q * 64 + 8 * k + 4);
          acc = qmac2(w.x, ha.x, ha.y, acc);
          acc = qmac2(w.y, ha.z, ha.w, acc);
          acc = qmac2(w.z, hb.x, hb.y, acc);
          acc = qmac2(w.w, hb.z, hb.w, acc);
        }
        acc += __shfl_xor(acc, 1);
        acc += __shfl_xor(acc, 2);
        if (q == 0) s_h2[o] = sp_fast(acc * sc_m0 + bm0);
      }
      lbar();
      // ---- m1 (streamed int16): row o, quarter q over 64 ins ----
      {
        float acc = 0.f;
#pragma unroll
        for (int c = 0; c < 8; ++c) {
          uint4 w = wm1p[c * 1024];
          float4 ha = *(const float4*)(s_h2 + q * 64 + 8 * c);
          float4 hb = *(const float4*)(s_h2 + q * 64 + 8 * c + 4);
          acc = qmac2(w.x, ha.x, ha.y, acc);
          acc = qmac2(w.y, ha.z, ha.w, acc);
          acc = qmac2(w.z, hb.x, hb.y, acc);
          acc = qmac2(w.w, hb.z, hb.w, acc);
        }
        acc += __shfl_xor(acc, 1);
        acc += __shfl_xor(acc, 2);
        if (q == 0) s_h3[o] = sp_fast(acc * sc_m1 + bm1);
      }
      lbar();
      // ---- L4 (streamed int16, 512KB half): 1 row/thread (row = t) ----
      {
        float za = 0.f, zb = 0.f;
#pragma unroll 4
        for (int cc = 0; cc < 32; cc += 2) {
          float4 ha0 = *(const float4*)(s_h3 + 8 * cc);
          float4 hb0 = *(const float4*)(s_h3 + 8 * cc + 4);
          uint4 w0 = wl4p[cc * 1024];
          float4 ha1 = *(const float4*)(s_h3 + 8 * cc + 8);
          float4 hb1 = *(const float4*)(s_h3 + 8 * cc + 12);
          uint4 w1 = wl4p[(cc + 1) * 1024];
          za = qmac2(w0.x, ha0.x, ha0.y, za); za = qmac2(w0.y, ha0.z, ha0.w, za);
          za = qmac2(w0.z, hb0.x, hb0.y, za); za = qmac2(w0.w, hb0.z, hb0.w, za);
          zb = qmac2(w1.x, ha1.x, ha1.y, zb); zb = qmac2(w1.y, ha1.z, ha1.w, zb);
          zb = qmac2(w1.z, hb1.x, hb1.y, zb); zb = qmac2(w1.w, hb1.z, hb1.w, zb);
        }
        float z = za + zb;
        float kv = tanh_fast(fmaf(z, scl4f, vbf)) * s_dxt[ti][dL];
        kv += __shfl_xor(kv, 1);
        kv += __shfl_xor(kv, 2);
        kv += __shfl_xor(kv, 4);
        kv += __shfl_xor(kv, 8);
        if (dL == 0) {
          const uint32_t T = (uint32_t)(l * 4 + e + 1);   // this publish
          s_k[(s << 6) + hl] = kv;
          st_coh8(ex_own + ((T & 1) << 6) + hl, pack_tf(kv, T));
        }
      }
      lbar();
    }
  }

  // -------- epilogue: consume final k (tag 252), write out row 63 ---------
  if (s == 0) {
    const float dtp = s_ts[63] - s_ts[62];
    if (t < 64) {
      u64t* pw = expart + t;               // tag 252 -> bank 0
      u64t v = ld_coh8(pw);
      uint32_t n = 0;
      while ((uint32_t)(v >> 32) != 252u) {
        if (n > 8) __builtin_amdgcn_s_sleep(8);
        else       __builtin_amdgcn_s_sleep(1);
        if (++n > (1u << 14)) break;
        v = ld_coh8(pw);
      }
      int h = 64 + t;                      // s==0 -> partner half is 64..127
      float ka = s_ka[h] + low_f(v);
      float yn = fmaf(dtp * (1.f / 6.f), ka, s_y[h]);
      out[(size_t)b * 8192 + 63 * 128 + h] = (s_ts[63] <= tm) ? yn : -99.f;
    } else if (t < 128) {
      int h = t - 64;                      // own half 0..63
      float ka = s_ka[h] + s_k[h];
      float yn = fmaf(dtp * (1.f / 6.f), ka, s_y[h]);
      out[(size_t)b * 8192 + 63 * 128 + h] = (s_ts[63] <= tm) ? yn : -99.f;
    }
  }
}

extern "C" void kernel_launch(void* const* d_in, const int* in_sizes, int n_in,
                              void* d_out, int out_size, void* d_ws, size_t ws_size,
                              hipStream_t stream) {
  const float* ts     = (const float*)d_in[0];
  const float* tsi    = (const float*)d_in[1];
  const float* obs    = (const float*)d_in[2];
  const float* tmaxp  = (const float*)d_in[3];
  const float* i_win  = (const float*)d_in[4];
  const float* i_bin  = (const float*)d_in[5];
  const float* i_wmid = (const float*)d_in[6];
  const float* i_bmid = (const float*)d_in[7];
  const float* i_wout = (const float*)d_in[8];
  const float* i_bout = (const float*)d_in[9];
  const float* v_win  = (const float*)d_in[10];
  const float* v_bin  = (const float*)d_in[11];
  const float* v_wmid = (const float*)d_in[12];
  const float* v_bmid = (const float*)d_in[13];
  const float* v_wout = (const float*)d_in[14];
  const float* v_bout = (const float*)d_in[15];

  unsigned char* wsb = (unsigned char*)d_ws;   // needs 1,649,664 B

  // zero the k-exchange region (tags restart each launch; graph-safe)
  size_t exbytes = 262144;
  if (EX_OFF + exbytes > ws_size) exbytes = (ws_size > EX_OFF) ? ws_size - EX_OFF : 0;
  (void)hipMemsetAsync(wsb + EX_OFF, 0, exbytes, stream);

  prep_kernel<<<dim3(2816), dim3(64), 0, stream>>>(v_win, v_wmid, v_wout, wsb);
  ncde_kernel<<<dim3(NB), dim3(NTHR), 0, stream>>>(
      ts, tsi, obs, tmaxp,
      i_win, i_bin, i_wmid, i_bmid, i_wout, i_bout,
      v_wmid, v_bin, v_bmid, v_bout,
      wsb, (float*)d_out);
}